// Round 7
// baseline (338.175 us; speedup 1.0000x reference)
//
#include <hip/hip_runtime.h>
#include <stdint.h>

typedef __bf16 bf16;
typedef __bf16 bf16x4 __attribute__((ext_vector_type(4)));
typedef __bf16 bf16x8 __attribute__((ext_vector_type(8)));
typedef float floatx4 __attribute__((ext_vector_type(4)));

#define B_   2
#define T_   2048
#define E_   2048
#define G_   4
#define QPG_ 4
#define D_   128
#define H_   16        // G*QPG
#define NQ   2048      // H*D
#define NKV  1024      // 2*G*D
#define NQKV 3072
#define M_   4096      // B*T

// async global->LDS, 16B/lane; LDS dst is wave-uniform base + lane*16
__device__ __forceinline__ void gload_lds16(const void* g, void* l) {
  __builtin_amdgcn_global_load_lds(
      (__attribute__((address_space(1))) unsigned int*)g,
      (__attribute__((address_space(3))) unsigned int*)l,
      16, 0, 0);
}

// ---- LDS XOR swizzle for [row][32-elem] tiles staged via global_load_lds ----
// Slot s (16B) of row R holds global chunk s ^ (R&3) ^ ((R>>2)&3).
__device__ __forceinline__ int swz_stage_col(int lane) {
  return (((lane & 3) ^ ((lane >> 2) & 3) ^ ((lane >> 4) & 3))) * 8;
}

// ---------------- conversion kernels ----------------

__global__ void cast_f32_bf16(const float* __restrict__ in, bf16* __restrict__ out, int n4) {
  int i = blockIdx.x * blockDim.x + threadIdx.x;
  if (i < n4) {
    float4 v = ((const float4*)in)[i];
    bf16x4 o = {(bf16)v.x, (bf16)v.y, (bf16)v.z, (bf16)v.w};
    ((bf16x4*)out)[i] = o;
  }
}

// in: R x C f32 (row-major). out: C x R bf16, row stride out_stride.
__global__ void transpose_cast(const float* __restrict__ in, bf16* __restrict__ out,
                               int R, int C, int out_stride) {
  __shared__ float tile[64][65];
  int r0 = blockIdx.x * 64, c0 = blockIdx.y * 64;
  int tx = threadIdx.x & 63, ty = threadIdx.x >> 6;
  for (int i = ty; i < 64; i += 4)
    tile[i][tx] = in[(size_t)(r0 + i) * C + c0 + tx];
  __syncthreads();
  for (int i = ty; i < 64; i += 4)
    out[(size_t)(c0 + i) * out_stride + r0 + tx] = (bf16)tile[tx][i];
}

__global__ void concat_bias(const float* __restrict__ bq, const float* __restrict__ bkv,
                            float* __restrict__ out) {
  int i = blockIdx.x * 256 + threadIdx.x;  // grid covers exactly 3072
  out[i] = (i < NQ) ? bq[i] : bkv[i - NQ];
}

// ---------------- PE table (accurate, built once per call) ----------------
// __sinf/v_sin_f32 takes revolutions and t*inv_freq reaches ~2047 rad (~326
// rev) -- outside reliable HW reduction. Precompute with libm sinf/cosf.
__global__ void build_pe(float* __restrict__ pe) {
  const int t = blockIdx.x, d = threadIdx.x;
  const int i2 = d & ~1;
  float inv = expf(-9.210340371976184f * (float)i2 * (1.0f / 128.0f));
  float ang = (float)t * inv;
  pe[t * 128 + d] = (d & 1) ? cosf(ang) : sinf(ang);
}

// ---------------- GEMM: out-proj  C = A(MxK) * Bt(NxK)^T ----------------
// m97 structure + XOR-swizzled LDS chunks.

__global__ __launch_bounds__(256, 2) void gemm_bt(
    const bf16* __restrict__ A, const bf16* __restrict__ Bt,
    float* __restrict__ Cout, int M, int N, int K) {
  __shared__ __align__(16) bf16 As[128 * 32];
  __shared__ __align__(16) bf16 Bs[128 * 32];
  const int tid = threadIdx.x;
  const int wave = tid >> 6, lane = tid & 63;
  const int quad = lane >> 4, c = lane & 15;
  const int m0 = blockIdx.x * 128, n0 = blockIdx.y * 128;
  const int wr = (wave >> 1) * 64, wc = (wave & 1) * 64;
  const int xsl = ((quad ^ (c & 3) ^ ((c >> 2) & 3)) & 3) * 8;

  floatx4 acc[4][4];
#pragma unroll
  for (int i = 0; i < 4; ++i)
#pragma unroll
    for (int j = 0; j < 4; ++j) acc[i][j] = (floatx4){0.f, 0.f, 0.f, 0.f};

  const int srow = wave * 32 + (lane >> 2);
  const int scol = swz_stage_col(lane);
  const bf16* Ap = A + (size_t)(m0 + srow) * K + scol;
  const bf16* Bp = Bt + (size_t)(n0 + srow) * K + scol;

  for (int k0 = 0; k0 < K; k0 += 32) {
#pragma unroll
    for (int ch = 0; ch < 2; ++ch) {
      gload_lds16(Ap + (size_t)ch * 16 * K + k0, &As[(wave * 2 + ch) * 512]);
      gload_lds16(Bp + (size_t)ch * 16 * K + k0, &Bs[(wave * 2 + ch) * 512]);
    }
    __syncthreads();
    bf16x8 af[4], bfr[4];
#pragma unroll
    for (int i = 0; i < 4; ++i) {
      af[i]  = *(const bf16x8*)(&As[(wr + i * 16 + c) * 32 + xsl]);
      bfr[i] = *(const bf16x8*)(&Bs[(wc + i * 16 + c) * 32 + xsl]);
    }
#pragma unroll
    for (int mi = 0; mi < 4; ++mi)
#pragma unroll
      for (int ni = 0; ni < 4; ++ni)
        acc[mi][ni] = __builtin_amdgcn_mfma_f32_16x16x32_bf16(af[mi], bfr[ni], acc[mi][ni], 0, 0, 0);
    __syncthreads();
  }

#pragma unroll
  for (int mi = 0; mi < 4; ++mi)
#pragma unroll
    for (int ni = 0; ni < 4; ++ni) {
      const int col = n0 + wc + ni * 16 + c;
#pragma unroll
      for (int r = 0; r < 4; ++r) {
        const int row = m0 + wr + mi * 16 + quad * 4 + r;
        Cout[(size_t)row * N + col] = acc[mi][ni][r];
      }
    }
}

// ---------------- fused QKV GEMM ----------------
// Epilogue adds bias + PE (table lookup) and writes DIRECTLY into attention
// layouts (Qb [b,h,t,d] scaled by log2e/sqrt(D); Kb [b,g,t,d]; Vtb [b,g,d,t]).
// Each 128-col n-block is purely Q, K, or V (N layout: 2048 Q | 4x(128K|128V)).

__global__ __launch_bounds__(256, 2) void gemm_qkv(
    const bf16* __restrict__ A, const bf16* __restrict__ Bt,
    const float* __restrict__ bias, const float* __restrict__ peT,
    bf16* __restrict__ Qb, bf16* __restrict__ Kb, bf16* __restrict__ Vtb) {
  const int N = NQKV, K = E_;
  __shared__ __align__(16) bf16 As[128 * 32];
  __shared__ __align__(16) bf16 Bs[128 * 32];
  const int tid = threadIdx.x;
  const int wave = tid >> 6, lane = tid & 63;
  const int quad = lane >> 4, c = lane & 15;
  const int m0 = blockIdx.x * 128, n0 = blockIdx.y * 128;
  const int wr = (wave >> 1) * 64, wc = (wave & 1) * 64;
  const int xsl = ((quad ^ (c & 3) ^ ((c >> 2) & 3)) & 3) * 8;

  floatx4 acc[4][4];
#pragma unroll
  for (int i = 0; i < 4; ++i)
#pragma unroll
    for (int j = 0; j < 4; ++j) acc[i][j] = (floatx4){0.f, 0.f, 0.f, 0.f};

  const int srow = wave * 32 + (lane >> 2);
  const int scol = swz_stage_col(lane);
  const bf16* Ap = A + (size_t)(m0 + srow) * K + scol;
  const bf16* Bp = Bt + (size_t)(n0 + srow) * K + scol;

  for (int k0 = 0; k0 < K; k0 += 32) {
#pragma unroll
    for (int ch = 0; ch < 2; ++ch) {
      gload_lds16(Ap + (size_t)ch * 16 * K + k0, &As[(wave * 2 + ch) * 512]);
      gload_lds16(Bp + (size_t)ch * 16 * K + k0, &Bs[(wave * 2 + ch) * 512]);
    }
    __syncthreads();
    bf16x8 af[4], bfr[4];
#pragma unroll
    for (int i = 0; i < 4; ++i) {
      af[i]  = *(const bf16x8*)(&As[(wr + i * 16 + c) * 32 + xsl]);
      bfr[i] = *(const bf16x8*)(&Bs[(wc + i * 16 + c) * 32 + xsl]);
    }
#pragma unroll
    for (int mi = 0; mi < 4; ++mi)
#pragma unroll
      for (int ni = 0; ni < 4; ++ni)
        acc[mi][ni] = __builtin_amdgcn_mfma_f32_16x16x32_bf16(af[mi], bfr[ni], acc[mi][ni], 0, 0, 0);
    __syncthreads();
  }

  const float scale = 0.12751745f;  // log2(e)/sqrt(128)
#pragma unroll
  for (int ni = 0; ni < 4; ++ni) {
    const int col = n0 + wc + ni * 16 + c;
    const float bv = bias[col];
#pragma unroll
    for (int mi = 0; mi < 4; ++mi) {
#pragma unroll
      for (int r = 0; r < 4; ++r) {
        const int row = m0 + wr + mi * 16 + quad * 4 + r;
        const int bb = row >> 11, t = row & 2047;
        float v = acc[mi][ni][r] + bv;
        if (col < NQ) {                       // Q (uniform per n-block)
          const int h = col >> 7, d = col & 127;
          Qb[((size_t)(bb * H_ + h) * T_ + t) * D_ + d] =
              (bf16)((v + peT[t * 128 + d]) * scale);
        } else {
          const int cc = col - NQ, g = cc >> 8, w2 = cc & 255;
          if (w2 < 128) {                     // K
            Kb[((size_t)(bb * G_ + g) * T_ + t) * D_ + w2] =
                (bf16)(v + peT[t * 128 + w2]);
          } else {                            // V -> transposed [d][t]
            Vtb[((size_t)(bb * G_ + g) * D_ + (w2 - 128)) * T_ + t] = (bf16)v;
          }
        }
      }
    }
  }
}

// ---------------- flash attention v6b ----------------
// 2 waves x 32 q-rows (128-thread block, same 64-q span, 37.1 KB LDS ->
// 4 blocks/CU). K/V fragments feed TWO m-tiles each: per-block-tile LDS
// traffic 88KB -> 56KB. No-max softmax (bounded scores), deferred row-sum,
// XOR-swizzled K/V, P via [q][key]/40.
// FIX vs v6: mask gate must compare max-key against the m-tile's MIN row
// (qw+mi*16), not max row -- the v6 gate skipped masking for mi=1 diagonal
// tiles, leaking up to 15 future keys for half of all rows.

__global__ __launch_bounds__(128, 2) void flash_attn(
    const bf16* __restrict__ Qb, const bf16* __restrict__ Kb,
    const bf16* __restrict__ Vt, bf16* __restrict__ Ob) {
  const int qt = (blockIdx.x + blockIdx.y) & 31;  // balance: CU's blocks differ in qt
  const int bh = blockIdx.y;
  const int b = bh >> 4, h = bh & 15, g = h >> 2;
  const int tid = threadIdx.x;
  const int wave = tid >> 6, lane = tid & 63;
  const int quad = lane >> 4, c = lane & 15;
  const int xsl = ((quad ^ (c & 3) ^ ((c >> 2) & 3)) & 3) * 8;

  __shared__ __align__(16) bf16 Ks[2][4][32 * 32];  // [buf][d-chunk][key][32] 16 KB
  __shared__ __align__(16) bf16 Vs[2][4][32 * 32];  // [buf][d-chunk][d][32]   16 KB
  __shared__ __align__(16) bf16 Pq[2][32 * 40];     // per-wave P [q][key], stride 40

  const int q0 = qt * 64;
  const int qw = q0 + wave * 32;  // this wave's 32 q-rows
  const bf16* Qh = Qb + (size_t)(b * H_ + h) * T_ * D_;
  bf16x8 qf[2][4];
#pragma unroll
  for (int mi = 0; mi < 2; ++mi)
#pragma unroll
    for (int ks = 0; ks < 4; ++ks)
      qf[mi][ks] = *(const bf16x8*)(Qh + (size_t)(qw + mi * 16 + c) * D_ + ks * 32 + quad * 8);

  floatx4 acc[2][8];
#pragma unroll
  for (int mi = 0; mi < 2; ++mi)
#pragma unroll
    for (int i = 0; i < 8; ++i) acc[mi][i] = (floatx4){0.f, 0.f, 0.f, 0.f};
  float rsum[2][4] = {{0.f, 0.f, 0.f, 0.f}, {0.f, 0.f, 0.f, 0.f}};

  const bf16* Kg = Kb + (size_t)(b * G_ + g) * T_ * D_;
  const bf16* Vg = Vt + (size_t)(b * G_ + g) * D_ * T_;
  const int slr = lane >> 2;
  const int slc = swz_stage_col(lane);
  const int nt = 2 * qt + 2;  // 32-key tiles

  // stage key-tile t into buffer bu: wave w owns d-chunks {2w, 2w+1}
  auto stage = [&](int t, int bu) {
    const int k0 = t * 32;
#pragma unroll
    for (int cc = 0; cc < 2; ++cc) {
      const int ch = wave * 2 + cc;
#pragma unroll
      for (int hh = 0; hh < 2; ++hh)
        gload_lds16(Kg + (size_t)(k0 + hh * 16 + slr) * D_ + ch * 32 + slc,
                    &Ks[bu][ch][hh * 16 * 32]);
#pragma unroll
      for (int hh = 0; hh < 2; ++hh)
        gload_lds16(Vg + (size_t)(ch * 32 + hh * 16 + slr) * T_ + k0 + slc,
                    &Vs[bu][ch][hh * 16 * 32]);
    }
  };

  stage(0, 0);

  for (int j = 0; j < nt; ++j) {
    __syncthreads();  // buf[j&1] ready; prev tile's LDS reads done
    if (j + 1 < nt) stage(j + 1, (j + 1) & 1);

    const bf16* Kt  = &Ks[j & 1][0][0];
    const bf16* Vtl = &Vs[j & 1][0][0];

    // S = Q K^T : (2 m-tiles x 16q) x 32k; kf shared across m-tiles
    floatx4 s[2][2];
#pragma unroll
    for (int mi = 0; mi < 2; ++mi)
#pragma unroll
      for (int n = 0; n < 2; ++n) s[mi][n] = (floatx4){0.f, 0.f, 0.f, 0.f};
#pragma unroll
    for (int ks = 0; ks < 4; ++ks)
#pragma unroll
      for (int n = 0; n < 2; ++n) {
        bf16x8 kf = *(const bf16x8*)(Kt + ks * 1024 + (n * 16 + c) * 32 + xsl);
#pragma unroll
        for (int mi = 0; mi < 2; ++mi)
          s[mi][n] = __builtin_amdgcn_mfma_f32_16x16x32_bf16(qf[mi][ks], kf, s[mi][n], 0, 0, 0);
      }

    // causal mask: needed iff max key (colb+31) > MIN row of this m-tile
    const int colb = j * 32;
#pragma unroll
    for (int mi = 0; mi < 2; ++mi) {
      if (colb + 31 > qw + mi * 16) {
        const int rowb = qw + mi * 16 + quad * 4;
#pragma unroll
        for (int n = 0; n < 2; ++n)
#pragma unroll
          for (int r = 0; r < 4; ++r)
            if (colb + n * 16 + c > rowb + r) s[mi][n][r] = -1e30f;
      }
    }

    // p = exp2(s); accumulate per-lane row sums; write P in A-layout [q][key]
    bf16* Pw = &Pq[wave][0];
#pragma unroll
    for (int mi = 0; mi < 2; ++mi)
#pragma unroll
      for (int n = 0; n < 2; ++n)
#pragma unroll
        for (int r = 0; r < 4; ++r) {
          float p = exp2f(s[mi][n][r]);
          rsum[mi][r] += p;
          Pw[(mi * 16 + quad * 4 + r) * 40 + n * 16 + c] = (bf16)p;
        }

    bf16x8 pf[2];
#pragma unroll
    for (int mi = 0; mi < 2; ++mi)
      pf[mi] = *(const bf16x8*)(&Pw[(mi * 16 + c) * 40 + quad * 8]);

    // O += P(32q x 32k) * V(32k x 128d); vf shared across m-tiles
#pragma unroll
    for (int nd = 0; nd < 8; ++nd) {
      bf16x8 vf = *(const bf16x8*)(Vtl + (nd >> 1) * 1024 + ((nd & 1) * 16 + c) * 32 + xsl);
#pragma unroll
      for (int mi = 0; mi < 2; ++mi)
        acc[mi][nd] = __builtin_amdgcn_mfma_f32_16x16x32_bf16(pf[mi], vf, acc[mi][nd], 0, 0, 0);
    }
  }

  // deferred row-sum reduction across the 16 lanes (c) of each quad-row
#pragma unroll
  for (int off = 1; off < 16; off <<= 1)
#pragma unroll
    for (int mi = 0; mi < 2; ++mi)
#pragma unroll
      for (int r = 0; r < 4; ++r) rsum[mi][r] += __shfl_xor(rsum[mi][r], off);

#pragma unroll
  for (int mi = 0; mi < 2; ++mi) {
    float linv[4];
#pragma unroll
    for (int r = 0; r < 4; ++r) linv[r] = 1.f / rsum[mi][r];
#pragma unroll
    for (int nd = 0; nd < 8; ++nd) {
      const int dd = nd * 16 + c;
#pragma unroll
      for (int r = 0; r < 4; ++r) {
        const int trow = qw + mi * 16 + quad * 4 + r;
        Ob[((size_t)(b * T_ + trow)) * NQ + h * D_ + dd] = (bf16)(acc[mi][nd][r] * linv[r]);
      }
    }
  }
}

// ---------------- launch ----------------

extern "C" void kernel_launch(void* const* d_in, const int* in_sizes, int n_in,
                              void* d_out, int out_size, void* d_ws, size_t ws_size,
                              hipStream_t stream) {
  const float* x   = (const float*)d_in[0];
  const float* wq  = (const float*)d_in[1];
  const float* bq  = (const float*)d_in[2];
  const float* wkv = (const float*)d_in[3];
  const float* bkv = (const float*)d_in[4];
  const float* wo  = (const float*)d_in[5];
  float* out = (float*)d_out;

  char* p = (char*)d_ws;                                   // ~78 MB total
  bf16* xb    = (bf16*)p; p += (size_t)M_ * E_ * 2;        // 16 MB
  bf16* wqkvT = (bf16*)p; p += (size_t)NQKV * E_ * 2;      // 12 MB  [N=3072][K=2048]
  bf16* woT   = (bf16*)p; p += (size_t)E_ * NQ * 2;        // 8 MB   [N=2048][K=2048]
  float* biasq = (float*)p; p += 16384;                    // 3072 f32, padded
  float* peT  = (float*)p; p += (size_t)T_ * D_ * 4;       // 1 MB PE table
  bf16* Qb    = (bf16*)p; p += (size_t)B_ * H_ * T_ * D_ * 2;  // 16 MB
  bf16* Kb    = (bf16*)p; p += (size_t)B_ * G_ * T_ * D_ * 2;  // 4 MB
  bf16* Vtb   = (bf16*)p; p += (size_t)B_ * G_ * D_ * T_ * 2;  // 4 MB
  bf16* Ob    = (bf16*)p; p += (size_t)M_ * NQ * 2;            // 16 MB

  cast_f32_bf16<<<(M_ * E_ / 4) / 256, 256, 0, stream>>>(x, xb, M_ * E_ / 4);
  transpose_cast<<<dim3(E_ / 64, E_ / 64), 256, 0, stream>>>(wq, wqkvT, E_, E_, E_);
  transpose_cast<<<dim3(E_ / 64, NKV / 64), 256, 0, stream>>>(wkv, wqkvT + (size_t)NQ * E_, E_, NKV, E_);
  transpose_cast<<<dim3(E_ / 64, E_ / 64), 256, 0, stream>>>(wo, woT, NQ, E_, NQ);
  concat_bias<<<NQKV / 256, 256, 0, stream>>>(bq, bkv, biasq);
  build_pe<<<T_, 128, 0, stream>>>(peT);

  gemm_qkv<<<dim3(M_ / 128, NQKV / 128), 256, 0, stream>>>(xb, wqkvT, biasq, peT, Qb, Kb, Vtb);
  flash_attn<<<dim3(T_ / 64, B_ * H_), 128, 0, stream>>>(Qb, Kb, Vtb, Ob);
  gemm_bt<<<dim3(M_ / 128, E_ / 128), 256, 0, stream>>>(Ob, woT, out, M_, E_, NQ);
}